// Round 5
// baseline (333.277 us; speedup 1.0000x reference)
//
#include <hip/hip_runtime.h>
#include <hip/hip_bf16.h>
#include <cstddef>
#include <cstdint>

#define NYV 64
#define NUV 64
#define NHID 512
#define NH2 256
#define NBATCH 64
#define CHUNK 64            // known-good geometry (R2). CHUNK=32 is poisoned.
#define NCHUNK 16
#define XP 520              // Xl row pitch (bf16 units) -> 1040 B, breaks pow2 stride
#define UP 72               // Ul row pitch (bf16 units) -> 144 B
#define BMK 4096            // Bmod K = CHUNK*NUV

typedef __attribute__((ext_vector_type(8))) short bf16x8;
typedef __attribute__((ext_vector_type(4))) float f32x4;
typedef __attribute__((ext_vector_type(8))) short short8v;

__device__ __forceinline__ uint f2bf(float f) {
    union { __hip_bfloat16 h; ushort s; } u;
    u.h = __float2bfloat16(f);
    return (uint)u.s;
}
__device__ __forceinline__ float bf2f_lo(uint d) {
    union { uint u; float f; } v; v.u = d << 16; return v.f;
}
__device__ __forceinline__ float bf2f_hi(uint d) {
    union { uint u; float f; } v; v.u = d & 0xffff0000u; return v.f;
}

// h-permutation: h' = 2p (real of pair p) / 2p+1 (imag of pair p)
// orig(h') = (h'>>1) + (h'&1)*256

// ---------------------------------------------------------------------------
// k_bmod: Bmod[2p  ][j*64+u] = cr_j*B[p][u] - ci_j*B[p+256][u]
//         Bmod[2p+1][j*64+u] = ci_j*B[p][u] + cr_j*B[p+256][u]
// with (cr_j, ci_j) = lambda_p^(63-j). grid=256 (p), block=64 (j).
// ---------------------------------------------------------------------------
__global__ __launch_bounds__(64) void k_bmod(
    const float* __restrict__ B, const float* __restrict__ lr,
    const float* __restrict__ li, short* __restrict__ Bmod)
{
    const int p = blockIdx.x;      // 0..255
    const int j = threadIdx.x;     // 0..63
    __shared__ float Bl[2][NUV];
    Bl[0][j] = B[p * NUV + j];
    Bl[1][j] = B[(p + NH2) * NUV + j];
    __syncthreads();

    const float Lr = lr[p], Li = li[p];
    float cr = 1.f, ci = 0.f;
    const int m = (CHUNK - 1) - j;
    for (int i = 0; i < m; ++i) {
        const float nr = cr * Lr - ci * Li;
        const float ni = cr * Li + ci * Lr;
        cr = nr; ci = ni;
    }

    short* r0 = Bmod + (size_t)(2 * p)     * BMK + j * NUV;
    short* r1 = Bmod + (size_t)(2 * p + 1) * BMK + j * NUV;
    #pragma unroll
    for (int u0 = 0; u0 < NUV; u0 += 8) {
        short8v s0, s1;
        #pragma unroll
        for (int k = 0; k < 8; ++k) {
            const float b1 = Bl[0][u0 + k], b2 = Bl[1][u0 + k];
            s0[k] = (short)f2bf(cr * b1 - ci * b2);
            s1[k] = (short)f2bf(ci * b1 + cr * b2);
        }
        *(short8v*)(r0 + u0) = s0;
        *(short8v*)(r1 + u0) = s1;
    }
}

// ---------------------------------------------------------------------------
// k_bgemm: le[c][b][h'] = sum_{jj,u} Bmod[h'][jj*64+u] * U[t0+jj][b][u]
// Pure MFMA, no barriers. grid (16 c, 2 mb), 512 threads (8 waves).
// Wave w owns h'-tiles (mb*256 + (w*2+mt)*16), mt in {0,1}; all 4 b-tiles.
// ---------------------------------------------------------------------------
__global__ __launch_bounds__(512) void k_bgemm(
    const float* __restrict__ U, const short* __restrict__ Bmod,
    float* __restrict__ carr)
{
    const int c  = blockIdx.x;
    const int mb = blockIdx.y;
    const int tid  = threadIdx.x;
    const int lane = tid & 63;
    const int w    = tid >> 6;          // 0..7
    const int lm   = lane & 15;
    const int lg   = lane >> 4;
    const int t0   = c * CHUNK;

    f32x4 acc[2][4];
    #pragma unroll
    for (int mt = 0; mt < 2; ++mt)
        #pragma unroll
        for (int nt = 0; nt < 4; ++nt)
            acc[mt][nt] = (f32x4){0.f, 0.f, 0.f, 0.f};

    #pragma unroll 4
    for (int jj = 0; jj < CHUNK; ++jj) {
        const float* ub = U + (size_t)(t0 + jj) * (NBATCH * NUV);
        // B-frags (U side): col b = nt*16+lm, k = ks*32 + lg*8 + j
        bf16x8 uf[4][2];
        #pragma unroll
        for (int nt = 0; nt < 4; ++nt) {
            const float* ur = ub + (nt * 16 + lm) * NUV;
            #pragma unroll
            for (int ks = 0; ks < 2; ++ks) {
                const float* q = ur + ks * 32 + lg * 8;
                const float4 g0 = *(const float4*)(q);
                const float4 g1 = *(const float4*)(q + 4);
                bf16x8 t8;
                t8[0]=(short)f2bf(g0.x); t8[1]=(short)f2bf(g0.y);
                t8[2]=(short)f2bf(g0.z); t8[3]=(short)f2bf(g0.w);
                t8[4]=(short)f2bf(g1.x); t8[5]=(short)f2bf(g1.y);
                t8[6]=(short)f2bf(g1.z); t8[7]=(short)f2bf(g1.w);
                uf[nt][ks] = t8;
            }
        }
        // A-frags (Bmod side, already bf16): row h' = mb*256+(w*2+mt)*16+lm
        #pragma unroll
        for (int mt = 0; mt < 2; ++mt) {
            const short* ar = Bmod + (size_t)(mb * 256 + (w * 2 + mt) * 16 + lm) * BMK
                            + jj * NUV + lg * 8;
            const bf16x8 a0 = *(const bf16x8*)(ar);
            const bf16x8 a1 = *(const bf16x8*)(ar + 32);
            #pragma unroll
            for (int nt = 0; nt < 4; ++nt) {
                acc[mt][nt] = __builtin_amdgcn_mfma_f32_16x16x32_bf16(a0, uf[nt][0], acc[mt][nt], 0, 0, 0);
                acc[mt][nt] = __builtin_amdgcn_mfma_f32_16x16x32_bf16(a1, uf[nt][1], acc[mt][nt], 0, 0, 0);
            }
        }
    }

    // store: D row = h' = base + lg*4 + r, col = b = nt*16 + lm
    #pragma unroll
    for (int mt = 0; mt < 2; ++mt) {
        #pragma unroll
        for (int nt = 0; nt < 4; ++nt) {
            const int b  = nt * 16 + lm;
            const int hb = mb * 256 + (w * 2 + mt) * 16 + lg * 4;
            float4 v;
            v.x = acc[mt][nt][0]; v.y = acc[mt][nt][1];
            v.z = acc[mt][nt][2]; v.w = acc[mt][nt][3];
            *(float4*)&carr[((size_t)c * NBATCH + b) * NHID + hb] = v;
        }
    }
}

// ---------------------------------------------------------------------------
// Pass 3 (R2 VERBATIM, CHUNK=64): GEMM1 -> scan (seeded) -> GEMM2 -> Y.
// ---------------------------------------------------------------------------
template<bool FINAL>
__global__ __launch_bounds__(256) void k_scan(
    const float* __restrict__ U, const float* __restrict__ B,
    const float* __restrict__ lr, const float* __restrict__ li,
    const float* __restrict__ W, const float* __restrict__ bx2y,
    float* __restrict__ carr, float* __restrict__ Y)
{
    __shared__ short Xl[CHUNK * XP];   // 66,560 B
    __shared__ short Ul[CHUNK * UP];   //  9,216 B

    const int b  = blockIdx.x;
    const int c  = blockIdx.y;
    const int t0 = c * CHUNK;
    const int tid  = threadIdx.x;
    const int lane = tid & 63;
    const int w    = tid >> 6;          // wave 0..3
    const int lm   = lane & 15;
    const int lg   = lane >> 4;

    // ---- stage U chunk (f32 -> bf16) into Ul[t][u] ----
    {
        const int t = tid >> 2, q = (tid & 3) * 16;
        const float* up = U + ((size_t)(t0 + t) * NBATCH + b) * NUV + q;
        const float4 f0 = *(const float4*)(up + 0);
        const float4 f1 = *(const float4*)(up + 4);
        const float4 f2 = *(const float4*)(up + 8);
        const float4 f3 = *(const float4*)(up + 12);
        short8v s0, s1;
        s0[0]=(short)f2bf(f0.x); s0[1]=(short)f2bf(f0.y);
        s0[2]=(short)f2bf(f0.z); s0[3]=(short)f2bf(f0.w);
        s0[4]=(short)f2bf(f1.x); s0[5]=(short)f2bf(f1.y);
        s0[6]=(short)f2bf(f1.z); s0[7]=(short)f2bf(f1.w);
        s1[0]=(short)f2bf(f2.x); s1[1]=(short)f2bf(f2.y);
        s1[2]=(short)f2bf(f2.z); s1[3]=(short)f2bf(f2.w);
        s1[4]=(short)f2bf(f3.x); s1[5]=(short)f2bf(f3.y);
        s1[6]=(short)f2bf(f3.z); s1[7]=(short)f2bf(f3.w);
        *(short8v*)&Ul[t*UP + q]     = s0;
        *(short8v*)&Ul[t*UP + q + 8] = s1;
    }
    __syncthreads();

    // ---- GEMM1: wave w owns h'-tiles [w*8, w*8+8), all 4 t-tiles ----
    {
        bf16x8 ufrag[4][2];
        #pragma unroll
        for (int nt = 0; nt < 4; ++nt)
            #pragma unroll
            for (int ks = 0; ks < 2; ++ks)
                ufrag[nt][ks] = *(const bf16x8*)&Ul[(nt*16 + lm)*UP + lg*8 + ks*32];

        #pragma unroll
        for (int i = 0; i < 8; ++i) {
            const int mt = w*8 + i;
            const int hp = mt*16 + lm;                    // A-row h'
            const int ho = (hp >> 1) + ((hp & 1) << 8);   // orig h
            bf16x8 a[2];
            #pragma unroll
            for (int ks = 0; ks < 2; ++ks) {
                const float* bp = B + ho*NUV + lg*8 + ks*32;
                const float4 g0 = *(const float4*)(bp);
                const float4 g1 = *(const float4*)(bp + 4);
                bf16x8 t8;
                t8[0]=(short)f2bf(g0.x); t8[1]=(short)f2bf(g0.y);
                t8[2]=(short)f2bf(g0.z); t8[3]=(short)f2bf(g0.w);
                t8[4]=(short)f2bf(g1.x); t8[5]=(short)f2bf(g1.y);
                t8[6]=(short)f2bf(g1.z); t8[7]=(short)f2bf(g1.w);
                a[ks] = t8;
            }
            #pragma unroll
            for (int nt = 0; nt < 4; ++nt) {
                f32x4 acc = {0.f, 0.f, 0.f, 0.f};
                acc = __builtin_amdgcn_mfma_f32_16x16x32_bf16(a[0], ufrag[nt][0], acc, 0, 0, 0);
                acc = __builtin_amdgcn_mfma_f32_16x16x32_bf16(a[1], ufrag[nt][1], acc, 0, 0, 0);
                const int t  = nt*16 + lm;
                const int hb = mt*16 + lg*4;
                uint2 pk;
                pk.x = f2bf(acc[0]) | (f2bf(acc[1]) << 16);
                pk.y = f2bf(acc[2]) | (f2bf(acc[3]) << 16);
                *(uint2*)&Xl[t*XP + hb] = pk;
            }
        }
    }
    __syncthreads();

    // ---- scan: thread p owns complex pair (h'=2p, 2p+1) ----
    {
        const int p = tid;
        const float Lr = lr[p], Li = li[p];
        float x1, x2;
        if (FINAL) {
            const float* cp = carr + ((size_t)c*NBATCH + b)*NHID + 2*p;
            x1 = cp[0]; x2 = cp[1];
        } else { x1 = 0.f; x2 = 0.f; }
        #pragma unroll 8
        for (int t = 0; t < CHUNK; ++t) {
            const uint d = *(const uint*)&Xl[t*XP + 2*p];
            const float n1 = fmaf(Lr, x1, fmaf(-Li, x2, bf2f_lo(d)));
            const float n2 = fmaf(Li, x1, fmaf( Lr, x2, bf2f_hi(d)));
            x1 = n1; x2 = n2;
            if (FINAL) {
                const uint pk = f2bf(x1) | (f2bf(x2) << 16);
                *(uint*)&Xl[t*XP + 2*p] = pk;
            }
        }
        if (!FINAL) {
            float2* cp = (float2*)(carr + ((size_t)c*NBATCH + b)*NHID + 2*p);
            *cp = make_float2(x1, x2);
        }
    }

    if constexpr (FINAL) {
        __syncthreads();
        // ---- GEMM2: wave w owns y-tile w; 4 t-tiles; K = 512 ----
        const int y = w*16 + lm;
        const float bias = bx2y[y];
        f32x4 acc2[4];
        #pragma unroll
        for (int mt = 0; mt < 4; ++mt) acc2[mt] = (f32x4){bias, bias, bias, bias};

        #pragma unroll
        for (int ks = 0; ks < 16; ++ks) {
            const int p0 = lg*4 + ks*16;
            const float4 wr = *(const float4*)(W + (size_t)y*NHID + p0);
            const float4 wi = *(const float4*)(W + (size_t)y*NHID + NH2 + p0);
            bf16x8 bf;
            bf[0]=(short)f2bf(wr.x); bf[1]=(short)f2bf(wi.x);
            bf[2]=(short)f2bf(wr.y); bf[3]=(short)f2bf(wi.y);
            bf[4]=(short)f2bf(wr.z); bf[5]=(short)f2bf(wi.z);
            bf[6]=(short)f2bf(wr.w); bf[7]=(short)f2bf(wi.w);
            const int kb = lg*8 + ks*32;
            #pragma unroll
            for (int mt = 0; mt < 4; ++mt) {
                const bf16x8 xa = *(const bf16x8*)&Xl[(mt*16 + lm)*XP + kb];
                acc2[mt] = __builtin_amdgcn_mfma_f32_16x16x32_bf16(xa, bf, acc2[mt], 0, 0, 0);
            }
        }
        #pragma unroll
        for (int mt = 0; mt < 4; ++mt) {
            #pragma unroll
            for (int r = 0; r < 4; ++r) {
                const int t = mt*16 + lg*4 + r;
                Y[((size_t)(t0 + t)*NBATCH + b)*NYV + y] = acc2[mt][r];
            }
        }
    }
}

// ---------------------------------------------------------------------------
// Carry propagation (R2 VERBATIM): x0 = y0@Wy2x^T + by2x; Lambda^64;
// sequential over 16 chunks, in place.
// ---------------------------------------------------------------------------
__global__ __launch_bounds__(256) void k_carry_prop(
    const float* __restrict__ y0, const float* __restrict__ Wy2x,
    const float* __restrict__ by2x,
    const float* __restrict__ lr, const float* __restrict__ li,
    float* __restrict__ carr)
{
    const int b = blockIdx.x;
    const int p = threadIdx.x;            // 0..255

    float x1 = by2x[p], x2 = by2x[p + NH2];
    #pragma unroll 8
    for (int yv = 0; yv < NYV; ++yv) {
        const float y0v = y0[b * NYV + yv];
        x1 = fmaf(y0v, Wy2x[p * NYV + yv], x1);
        x2 = fmaf(y0v, Wy2x[(p + NH2) * NYV + yv], x2);
    }

    // Lambda^64 by 6 squarings
    float cr = lr[p], ci = li[p];
    #pragma unroll
    for (int k = 0; k < 6; ++k) {
        const float nr = cr*cr - ci*ci;
        const float ni = 2.f*cr*ci;
        cr = nr; ci = ni;
    }

    for (int c = 0; c < NCHUNK; ++c) {
        float* cp = carr + ((size_t)c*NBATCH + b)*NHID + 2*p;
        const float le1 = cp[0];
        const float le2 = cp[1];
        cp[0] = x1; cp[1] = x2;
        const float n1 = cr*x1 - ci*x2 + le1;
        const float n2 = ci*x1 + cr*x2 + le2;
        x1 = n1; x2 = n2;
    }
}

extern "C" void kernel_launch(void* const* d_in, const int* in_sizes, int n_in,
                              void* d_out, int out_size, void* d_ws, size_t ws_size,
                              hipStream_t stream) {
    const float* y0   = (const float*)d_in[0];
    const float* U    = (const float*)d_in[1];
    const float* lr   = (const float*)d_in[2];
    const float* li   = (const float*)d_in[3];
    const float* B    = (const float*)d_in[4];
    const float* Wy2x = (const float*)d_in[5];
    const float* by2x = (const float*)d_in[6];
    const float* Wx2y = (const float*)d_in[7];
    const float* bx2y = (const float*)d_in[8];
    float* Y    = (float*)d_out;
    float* carr = (float*)d_ws;                                    // 2 MB
    short* Bmod = (short*)((char*)d_ws + (size_t)NCHUNK*NBATCH*NHID*4); // +4 MB

    k_bmod<<<dim3(NH2), 64, 0, stream>>>(B, lr, li, Bmod);
    k_bgemm<<<dim3(NCHUNK, 2), 512, 0, stream>>>(U, Bmod, carr);
    k_carry_prop<<<NBATCH, 256, 0, stream>>>(y0, Wy2x, by2x, lr, li, carr);
    k_scan<true><<<dim3(NBATCH, NCHUNK), 256, 0, stream>>>(U, B, lr, li, Wx2y, bx2y, carr, Y);
}

// Round 6
// 105.205 us; speedup vs baseline: 3.1679x; 3.1679x over previous
//
#include <hip/hip_runtime.h>
#include <hip/hip_bf16.h>
#include <cstddef>
#include <cstdint>

#define NYV 64
#define NUV 64
#define NHID 512
#define NH2 256
#define NBATCH 64
#define CHUNK 64            // known-good geometry (R2). CHUNK=32 is poisoned.
#define NCHUNK 16
#define XP 520              // Xl row pitch (bf16 units) -> 1040 B, breaks pow2 stride
#define UP 72               // Ul row pitch (bf16 units) -> 144 B
#define BMK 4096            // Bmod K = CHUNK*NUV
#define NTOT (16*64)        // total timesteps

typedef __attribute__((ext_vector_type(8))) short bf16x8;
typedef __attribute__((ext_vector_type(4))) float f32x4;
typedef __attribute__((ext_vector_type(8))) short short8v;

__device__ __forceinline__ uint f2bf(float f) {
    union { __hip_bfloat16 h; ushort s; } u;
    u.h = __float2bfloat16(f);
    return (uint)u.s;
}
__device__ __forceinline__ float bf2f_lo(uint d) {
    union { uint u; float f; } v; v.u = d << 16; return v.f;
}
__device__ __forceinline__ float bf2f_hi(uint d) {
    union { uint u; float f; } v; v.u = d & 0xffff0000u; return v.f;
}

// h-permutation: h' = 2p (real of pair p) / 2p+1 (imag of pair p)
// orig(h') = (h'>>1) + (h'&1)*256

// ---------------------------------------------------------------------------
// k_cvtU: U (f32, [t][b][u]) -> Ubf (bf16, same layout). 8 elems/thread,
// 2048 blocks x 256 thr covers 1024*64*64 = 4,194,304 elements exactly.
// ---------------------------------------------------------------------------
__global__ __launch_bounds__(256) void k_cvtU(
    const float* __restrict__ U, short* __restrict__ Ubf)
{
    const size_t g = ((size_t)blockIdx.x * 256 + threadIdx.x) * 8;
    const float4 f0 = *(const float4*)(U + g);
    const float4 f1 = *(const float4*)(U + g + 4);
    short8v s;
    s[0]=(short)f2bf(f0.x); s[1]=(short)f2bf(f0.y);
    s[2]=(short)f2bf(f0.z); s[3]=(short)f2bf(f0.w);
    s[4]=(short)f2bf(f1.x); s[5]=(short)f2bf(f1.y);
    s[6]=(short)f2bf(f1.z); s[7]=(short)f2bf(f1.w);
    *(short8v*)(Ubf + g) = s;
}

// ---------------------------------------------------------------------------
// k_bmod (R5-proven): Bmod[2p][j*64+u]   = cr_j*B[p][u] - ci_j*B[p+256][u]
//                     Bmod[2p+1][j*64+u] = ci_j*B[p][u] + cr_j*B[p+256][u]
// with (cr_j, ci_j) = lambda_p^(63-j). grid=256 (p), block=64 (j).
// ---------------------------------------------------------------------------
__global__ __launch_bounds__(64) void k_bmod(
    const float* __restrict__ B, const float* __restrict__ lr,
    const float* __restrict__ li, short* __restrict__ Bmod)
{
    const int p = blockIdx.x;      // 0..255
    const int j = threadIdx.x;     // 0..63
    __shared__ float Bl[2][NUV];
    Bl[0][j] = B[p * NUV + j];
    Bl[1][j] = B[(p + NH2) * NUV + j];
    __syncthreads();

    const float Lr = lr[p], Li = li[p];
    float cr = 1.f, ci = 0.f;
    const int m = (CHUNK - 1) - j;
    for (int i = 0; i < m; ++i) {
        const float nr = cr * Lr - ci * Li;
        const float ni = cr * Li + ci * Lr;
        cr = nr; ci = ni;
    }

    short* r0 = Bmod + (size_t)(2 * p)     * BMK + j * NUV;
    short* r1 = Bmod + (size_t)(2 * p + 1) * BMK + j * NUV;
    #pragma unroll
    for (int u0 = 0; u0 < NUV; u0 += 8) {
        short8v s0, s1;
        #pragma unroll
        for (int k = 0; k < 8; ++k) {
            const float b1 = Bl[0][u0 + k], b2 = Bl[1][u0 + k];
            s0[k] = (short)f2bf(cr * b1 - ci * b2);
            s1[k] = (short)f2bf(ci * b1 + cr * b2);
        }
        *(short8v*)(r0 + u0) = s0;
        *(short8v*)(r1 + u0) = s1;
    }
}

// ---------------------------------------------------------------------------
// k_bgemm_v2: le[c][b][h'] = sum_{jj,u} Bmod[h'][jj*64+u] * Ubf[t0+jj][b][u]
// grid (16 c, 8 mb, 2 kh) = 256 blocks, 256 thr (4 waves).
// Wave w owns 16 rows h' = mb*64 + w*16 + .., all 4 b-tiles; K-half kh.
// kh=0 -> carrA, kh=1 -> carrB (summed later in k_carry_prop).
// Row/col/store mappings identical to the R5-proven k_bgemm.
// ---------------------------------------------------------------------------
__global__ __launch_bounds__(256) void k_bgemm_v2(
    const short* __restrict__ Ubf, const short* __restrict__ Bmod,
    float* __restrict__ carrA, float* __restrict__ carrB)
{
    const int c  = blockIdx.x;
    const int mb = blockIdx.y;
    const int kh = blockIdx.z;
    const int tid  = threadIdx.x;
    const int lane = tid & 63;
    const int w    = tid >> 6;          // 0..3
    const int lm   = lane & 15;
    const int lg   = lane >> 4;
    const int t0   = c * CHUNK;

    f32x4 acc[4];
    #pragma unroll
    for (int nt = 0; nt < 4; ++nt) acc[nt] = (f32x4){0.f, 0.f, 0.f, 0.f};

    const int rowA = mb * 64 + w * 16 + lm;
    const short* arow = Bmod + (size_t)rowA * BMK + lg * 8;

    #pragma unroll 4
    for (int jj = 0; jj < 32; ++jj) {
        const int jjg = kh * 32 + jj;
        const short* ub = Ubf + (size_t)(t0 + jjg) * (NBATCH * NUV) + lg * 8;
        // A-frags (Bmod, bf16): k = jjg*64 + ks*32 + lg*8 + j
        const bf16x8 a0 = *(const bf16x8*)(arow + jjg * NUV);
        const bf16x8 a1 = *(const bf16x8*)(arow + jjg * NUV + 32);
        // B-frags (Ubf): col b = nt*16+lm, same k
        #pragma unroll
        for (int nt = 0; nt < 4; ++nt) {
            const short* ur = ub + (nt * 16 + lm) * NUV;
            const bf16x8 u0 = *(const bf16x8*)(ur);
            const bf16x8 u1 = *(const bf16x8*)(ur + 32);
            acc[nt] = __builtin_amdgcn_mfma_f32_16x16x32_bf16(a0, u0, acc[nt], 0, 0, 0);
            acc[nt] = __builtin_amdgcn_mfma_f32_16x16x32_bf16(a1, u1, acc[nt], 0, 0, 0);
        }
    }

    float* dst = kh ? carrB : carrA;
    const int hb = mb * 64 + w * 16 + lg * 4;
    #pragma unroll
    for (int nt = 0; nt < 4; ++nt) {
        const int b = nt * 16 + lm;
        float4 v;
        v.x = acc[nt][0]; v.y = acc[nt][1];
        v.z = acc[nt][2]; v.w = acc[nt][3];
        *(float4*)&dst[((size_t)c * NBATCH + b) * NHID + hb] = v;
    }
}

// ---------------------------------------------------------------------------
// Pass 3 (R2 VERBATIM, CHUNK=64): GEMM1 -> scan (seeded) -> GEMM2 -> Y.
// ---------------------------------------------------------------------------
template<bool FINAL>
__global__ __launch_bounds__(256) void k_scan(
    const float* __restrict__ U, const float* __restrict__ B,
    const float* __restrict__ lr, const float* __restrict__ li,
    const float* __restrict__ W, const float* __restrict__ bx2y,
    float* __restrict__ carr, float* __restrict__ Y)
{
    __shared__ short Xl[CHUNK * XP];   // 66,560 B
    __shared__ short Ul[CHUNK * UP];   //  9,216 B

    const int b  = blockIdx.x;
    const int c  = blockIdx.y;
    const int t0 = c * CHUNK;
    const int tid  = threadIdx.x;
    const int lane = tid & 63;
    const int w    = tid >> 6;          // wave 0..3
    const int lm   = lane & 15;
    const int lg   = lane >> 4;

    // ---- stage U chunk (f32 -> bf16) into Ul[t][u] ----
    {
        const int t = tid >> 2, q = (tid & 3) * 16;
        const float* up = U + ((size_t)(t0 + t) * NBATCH + b) * NUV + q;
        const float4 f0 = *(const float4*)(up + 0);
        const float4 f1 = *(const float4*)(up + 4);
        const float4 f2 = *(const float4*)(up + 8);
        const float4 f3 = *(const float4*)(up + 12);
        short8v s0, s1;
        s0[0]=(short)f2bf(f0.x); s0[1]=(short)f2bf(f0.y);
        s0[2]=(short)f2bf(f0.z); s0[3]=(short)f2bf(f0.w);
        s0[4]=(short)f2bf(f1.x); s0[5]=(short)f2bf(f1.y);
        s0[6]=(short)f2bf(f1.z); s0[7]=(short)f2bf(f1.w);
        s1[0]=(short)f2bf(f2.x); s1[1]=(short)f2bf(f2.y);
        s1[2]=(short)f2bf(f2.z); s1[3]=(short)f2bf(f2.w);
        s1[4]=(short)f2bf(f3.x); s1[5]=(short)f2bf(f3.y);
        s1[6]=(short)f2bf(f3.z); s1[7]=(short)f2bf(f3.w);
        *(short8v*)&Ul[t*UP + q]     = s0;
        *(short8v*)&Ul[t*UP + q + 8] = s1;
    }
    __syncthreads();

    // ---- GEMM1: wave w owns h'-tiles [w*8, w*8+8), all 4 t-tiles ----
    {
        bf16x8 ufrag[4][2];
        #pragma unroll
        for (int nt = 0; nt < 4; ++nt)
            #pragma unroll
            for (int ks = 0; ks < 2; ++ks)
                ufrag[nt][ks] = *(const bf16x8*)&Ul[(nt*16 + lm)*UP + lg*8 + ks*32];

        #pragma unroll
        for (int i = 0; i < 8; ++i) {
            const int mt = w*8 + i;
            const int hp = mt*16 + lm;                    // A-row h'
            const int ho = (hp >> 1) + ((hp & 1) << 8);   // orig h
            bf16x8 a[2];
            #pragma unroll
            for (int ks = 0; ks < 2; ++ks) {
                const float* bp = B + ho*NUV + lg*8 + ks*32;
                const float4 g0 = *(const float4*)(bp);
                const float4 g1 = *(const float4*)(bp + 4);
                bf16x8 t8;
                t8[0]=(short)f2bf(g0.x); t8[1]=(short)f2bf(g0.y);
                t8[2]=(short)f2bf(g0.z); t8[3]=(short)f2bf(g0.w);
                t8[4]=(short)f2bf(g1.x); t8[5]=(short)f2bf(g1.y);
                t8[6]=(short)f2bf(g1.z); t8[7]=(short)f2bf(g1.w);
                a[ks] = t8;
            }
            #pragma unroll
            for (int nt = 0; nt < 4; ++nt) {
                f32x4 acc = {0.f, 0.f, 0.f, 0.f};
                acc = __builtin_amdgcn_mfma_f32_16x16x32_bf16(a[0], ufrag[nt][0], acc, 0, 0, 0);
                acc = __builtin_amdgcn_mfma_f32_16x16x32_bf16(a[1], ufrag[nt][1], acc, 0, 0, 0);
                const int t  = nt*16 + lm;
                const int hb = mt*16 + lg*4;
                uint2 pk;
                pk.x = f2bf(acc[0]) | (f2bf(acc[1]) << 16);
                pk.y = f2bf(acc[2]) | (f2bf(acc[3]) << 16);
                *(uint2*)&Xl[t*XP + hb] = pk;
            }
        }
    }
    __syncthreads();

    // ---- scan: thread p owns complex pair (h'=2p, 2p+1) ----
    {
        const int p = tid;
        const float Lr = lr[p], Li = li[p];
        float x1, x2;
        if (FINAL) {
            const float* cp = carr + ((size_t)c*NBATCH + b)*NHID + 2*p;
            x1 = cp[0]; x2 = cp[1];
        } else { x1 = 0.f; x2 = 0.f; }
        #pragma unroll 8
        for (int t = 0; t < CHUNK; ++t) {
            const uint d = *(const uint*)&Xl[t*XP + 2*p];
            const float n1 = fmaf(Lr, x1, fmaf(-Li, x2, bf2f_lo(d)));
            const float n2 = fmaf(Li, x1, fmaf( Lr, x2, bf2f_hi(d)));
            x1 = n1; x2 = n2;
            if (FINAL) {
                const uint pk = f2bf(x1) | (f2bf(x2) << 16);
                *(uint*)&Xl[t*XP + 2*p] = pk;
            }
        }
        if (!FINAL) {
            float2* cp = (float2*)(carr + ((size_t)c*NBATCH + b)*NHID + 2*p);
            *cp = make_float2(x1, x2);
        }
    }

    if constexpr (FINAL) {
        __syncthreads();
        // ---- GEMM2: wave w owns y-tile w; 4 t-tiles; K = 512 ----
        const int y = w*16 + lm;
        const float bias = bx2y[y];
        f32x4 acc2[4];
        #pragma unroll
        for (int mt = 0; mt < 4; ++mt) acc2[mt] = (f32x4){bias, bias, bias, bias};

        #pragma unroll
        for (int ks = 0; ks < 16; ++ks) {
            const int p0 = lg*4 + ks*16;
            const float4 wr = *(const float4*)(W + (size_t)y*NHID + p0);
            const float4 wi = *(const float4*)(W + (size_t)y*NHID + NH2 + p0);
            bf16x8 bf;
            bf[0]=(short)f2bf(wr.x); bf[1]=(short)f2bf(wi.x);
            bf[2]=(short)f2bf(wr.y); bf[3]=(short)f2bf(wi.y);
            bf[4]=(short)f2bf(wr.z); bf[5]=(short)f2bf(wi.z);
            bf[6]=(short)f2bf(wr.w); bf[7]=(short)f2bf(wi.w);
            const int kb = lg*8 + ks*32;
            #pragma unroll
            for (int mt = 0; mt < 4; ++mt) {
                const bf16x8 xa = *(const bf16x8*)&Xl[(mt*16 + lm)*XP + kb];
                acc2[mt] = __builtin_amdgcn_mfma_f32_16x16x32_bf16(xa, bf, acc2[mt], 0, 0, 0);
            }
        }
        #pragma unroll
        for (int mt = 0; mt < 4; ++mt) {
            #pragma unroll
            for (int r = 0; r < 4; ++r) {
                const int t = mt*16 + lg*4 + r;
                Y[((size_t)(t0 + t)*NBATCH + b)*NYV + y] = acc2[mt][r];
            }
        }
    }
}

// ---------------------------------------------------------------------------
// Carry propagation (R2 structure; only change: le = carrA + carrB, the two
// K-halves of the chunk-local GEMM). Writes entry states into carrA in place.
// ---------------------------------------------------------------------------
__global__ __launch_bounds__(256) void k_carry_prop(
    const float* __restrict__ y0, const float* __restrict__ Wy2x,
    const float* __restrict__ by2x,
    const float* __restrict__ lr, const float* __restrict__ li,
    float* __restrict__ carr, const float* __restrict__ carrB)
{
    const int b = blockIdx.x;
    const int p = threadIdx.x;            // 0..255

    float x1 = by2x[p], x2 = by2x[p + NH2];
    #pragma unroll 8
    for (int yv = 0; yv < NYV; ++yv) {
        const float y0v = y0[b * NYV + yv];
        x1 = fmaf(y0v, Wy2x[p * NYV + yv], x1);
        x2 = fmaf(y0v, Wy2x[(p + NH2) * NYV + yv], x2);
    }

    // Lambda^64 by 6 squarings
    float cr = lr[p], ci = li[p];
    #pragma unroll
    for (int k = 0; k < 6; ++k) {
        const float nr = cr*cr - ci*ci;
        const float ni = 2.f*cr*ci;
        cr = nr; ci = ni;
    }

    for (int c = 0; c < NCHUNK; ++c) {
        const size_t off = ((size_t)c*NBATCH + b)*NHID + 2*p;
        float* cp = carr + off;
        const float le1 = cp[0] + carrB[off];
        const float le2 = cp[1] + carrB[off + 1];
        cp[0] = x1; cp[1] = x2;
        const float n1 = cr*x1 - ci*x2 + le1;
        const float n2 = ci*x1 + cr*x2 + le2;
        x1 = n1; x2 = n2;
    }
}

extern "C" void kernel_launch(void* const* d_in, const int* in_sizes, int n_in,
                              void* d_out, int out_size, void* d_ws, size_t ws_size,
                              hipStream_t stream) {
    const float* y0   = (const float*)d_in[0];
    const float* U    = (const float*)d_in[1];
    const float* lr   = (const float*)d_in[2];
    const float* li   = (const float*)d_in[3];
    const float* B    = (const float*)d_in[4];
    const float* Wy2x = (const float*)d_in[5];
    const float* by2x = (const float*)d_in[6];
    const float* Wx2y = (const float*)d_in[7];
    const float* bx2y = (const float*)d_in[8];
    float* Y    = (float*)d_out;
    char* ws = (char*)d_ws;
    float* carr  = (float*)(ws);                    // 2 MB
    short* Bmod  = (short*)(ws + (2u<<20));         // 4 MB
    float* carrB = (float*)(ws + (6u<<20));         // 2 MB
    short* Ubf   = (short*)(ws + (8u<<20));         // 8 MB

    k_cvtU<<<2048, 256, 0, stream>>>(U, Ubf);
    k_bmod<<<dim3(NH2), 64, 0, stream>>>(B, lr, li, Bmod);
    k_bgemm_v2<<<dim3(NCHUNK, 8, 2), 256, 0, stream>>>(Ubf, Bmod, carr, carrB);
    k_carry_prop<<<NBATCH, 256, 0, stream>>>(y0, Wy2x, by2x, lr, li, carr, carrB);
    k_scan<true><<<dim3(NBATCH, NCHUNK), 256, 0, stream>>>(U, B, lr, li, Wx2y, bx2y, carr, Y);
}

// Round 8
// 103.452 us; speedup vs baseline: 3.2216x; 1.0169x over previous
//
#include <hip/hip_runtime.h>
#include <hip/hip_bf16.h>
#include <cstddef>
#include <cstdint>

#define NYV 64
#define NUV 64
#define NHID 512
#define NH2 256
#define NBATCH 64
#define CHUNK 64            // known-good geometry. CHUNK=32 is poisoned (R3/R4).
#define NCHUNK 16
#define XP 520              // Xl row pitch (bf16 units) -> 1040 B, breaks pow2 stride
#define UP 72               // Ul row pitch (bf16 units) -> 144 B
#define BMK 4096            // Bmod K = CHUNK*NUV
#define NSPLIT 8            // K-split depth for bgemm
#define CPSZ (NCHUNK*NBATCH*NHID)   // floats per partial buffer (524288 = 2 MB)

typedef __attribute__((ext_vector_type(8))) short bf16x8;
typedef __attribute__((ext_vector_type(4))) float f32x4;
typedef __attribute__((ext_vector_type(8))) short short8v;

__device__ __forceinline__ uint f2bf(float f) {
    union { __hip_bfloat16 h; ushort s; } u;
    u.h = __float2bfloat16(f);
    return (uint)u.s;
}
__device__ __forceinline__ float bf2f_lo(uint d) {
    union { uint u; float f; } v; v.u = d << 16; return v.f;
}
__device__ __forceinline__ float bf2f_hi(uint d) {
    union { uint u; float f; } v; v.u = d & 0xffff0000u; return v.f;
}

// h-permutation: h' = 2p (real of pair p) / 2p+1 (imag of pair p)
// orig(h') = (h'>>1) + (h'&1)*256

// ---------------------------------------------------------------------------
// k_cvtU (R6-proven, verbatim): U (f32) -> Ubf (bf16), same [t][b][u] layout.
// ---------------------------------------------------------------------------
__global__ __launch_bounds__(256) void k_cvtU(
    const float* __restrict__ U, short* __restrict__ Ubf)
{
    const size_t g = ((size_t)blockIdx.x * 256 + threadIdx.x) * 8;
    const float4 f0 = *(const float4*)(U + g);
    const float4 f1 = *(const float4*)(U + g + 4);
    short8v s;
    s[0]=(short)f2bf(f0.x); s[1]=(short)f2bf(f0.y);
    s[2]=(short)f2bf(f0.z); s[3]=(short)f2bf(f0.w);
    s[4]=(short)f2bf(f1.x); s[5]=(short)f2bf(f1.y);
    s[6]=(short)f2bf(f1.z); s[7]=(short)f2bf(f1.w);
    *(short8v*)(Ubf + g) = s;
}

// ---------------------------------------------------------------------------
// k_bmod (R5-proven, verbatim): Bmod[2p][j*64+u]   = cr_j*B[p][u] - ci_j*B[p+256][u]
//                               Bmod[2p+1][j*64+u] = ci_j*B[p][u] + cr_j*B[p+256][u]
// with (cr_j, ci_j) = lambda_p^(63-j). grid=256 (p), block=64 (j).
// ---------------------------------------------------------------------------
__global__ __launch_bounds__(64) void k_bmod(
    const float* __restrict__ B, const float* __restrict__ lr,
    const float* __restrict__ li, short* __restrict__ Bmod)
{
    const int p = blockIdx.x;      // 0..255
    const int j = threadIdx.x;     // 0..63
    __shared__ float Bl[2][NUV];
    Bl[0][j] = B[p * NUV + j];
    Bl[1][j] = B[(p + NH2) * NUV + j];
    __syncthreads();

    const float Lr = lr[p], Li = li[p];
    float cr = 1.f, ci = 0.f;
    const int m = (CHUNK - 1) - j;
    for (int i = 0; i < m; ++i) {
        const float nr = cr * Lr - ci * Li;
        const float ni = cr * Li + ci * Lr;
        cr = nr; ci = ni;
    }

    short* r0 = Bmod + (size_t)(2 * p)     * BMK + j * NUV;
    short* r1 = Bmod + (size_t)(2 * p + 1) * BMK + j * NUV;
    #pragma unroll
    for (int u0 = 0; u0 < NUV; u0 += 8) {
        short8v s0, s1;
        #pragma unroll
        for (int k = 0; k < 8; ++k) {
            const float b1 = Bl[0][u0 + k], b2 = Bl[1][u0 + k];
            s0[k] = (short)f2bf(cr * b1 - ci * b2);
            s1[k] = (short)f2bf(ci * b1 + cr * b2);
        }
        *(short8v*)(r0 + u0) = s0;
        *(short8v*)(r1 + u0) = s1;
    }
}

// ---------------------------------------------------------------------------
// k_bgemm_v4: le partial over K-eighth kq. grid (16 c, 8 mb, 8 kq) = 1024
// blocks, 256 thr (4 waves) -> 4 waves/SIMD. Per-lane row/col/store mappings
// IDENTICAL to the R6-proven v2; only the K-split depth changed.
// Partial kq -> cPart + kq*CPSZ, summed in k_carry_prop in fixed order.
// ---------------------------------------------------------------------------
__global__ __launch_bounds__(256) void k_bgemm_v4(
    const short* __restrict__ Ubf, const short* __restrict__ Bmod,
    float* __restrict__ cPart)
{
    const int c  = blockIdx.x;
    const int mb = blockIdx.y;
    const int kq = blockIdx.z;          // 0..7
    const int tid  = threadIdx.x;
    const int lane = tid & 63;
    const int w    = tid >> 6;          // 0..3
    const int lm   = lane & 15;
    const int lg   = lane >> 4;
    const int t0   = c * CHUNK;

    f32x4 acc[4];
    #pragma unroll
    for (int nt = 0; nt < 4; ++nt) acc[nt] = (f32x4){0.f, 0.f, 0.f, 0.f};

    const int rowA = mb * 64 + w * 16 + lm;
    const short* arow = Bmod + (size_t)rowA * BMK + lg * 8;

    #pragma unroll 4
    for (int jj = 0; jj < CHUNK / NSPLIT; ++jj) {      // 8 trips
        const int jjg = kq * (CHUNK / NSPLIT) + jj;
        const short* ub = Ubf + (size_t)(t0 + jjg) * (NBATCH * NUV) + lg * 8;
        const bf16x8 a0 = *(const bf16x8*)(arow + jjg * NUV);
        const bf16x8 a1 = *(const bf16x8*)(arow + jjg * NUV + 32);
        #pragma unroll
        for (int nt = 0; nt < 4; ++nt) {
            const short* ur = ub + (nt * 16 + lm) * NUV;
            const bf16x8 u0 = *(const bf16x8*)(ur);
            const bf16x8 u1 = *(const bf16x8*)(ur + 32);
            acc[nt] = __builtin_amdgcn_mfma_f32_16x16x32_bf16(a0, u0, acc[nt], 0, 0, 0);
            acc[nt] = __builtin_amdgcn_mfma_f32_16x16x32_bf16(a1, u1, acc[nt], 0, 0, 0);
        }
    }

    float* dst = cPart + (size_t)kq * CPSZ;
    const int hb = mb * 64 + w * 16 + lg * 4;
    #pragma unroll
    for (int nt = 0; nt < 4; ++nt) {
        const int b = nt * 16 + lm;
        float4 v;
        v.x = acc[nt][0]; v.y = acc[nt][1];
        v.z = acc[nt][2]; v.w = acc[nt][3];
        *(float4*)&dst[((size_t)c * NBATCH + b) * NHID + hb] = v;
    }
}

// ---------------------------------------------------------------------------
// Pass 3 (R2/R5/R6-proven, VERBATIM): GEMM1 -> scan (seeded) -> GEMM2 -> Y.
// ---------------------------------------------------------------------------
template<bool FINAL>
__global__ __launch_bounds__(256) void k_scan(
    const float* __restrict__ U, const float* __restrict__ B,
    const float* __restrict__ lr, const float* __restrict__ li,
    const float* __restrict__ W, const float* __restrict__ bx2y,
    float* __restrict__ carr, float* __restrict__ Y)
{
    __shared__ short Xl[CHUNK * XP];   // 66,560 B
    __shared__ short Ul[CHUNK * UP];   //  9,216 B

    const int b  = blockIdx.x;
    const int c  = blockIdx.y;
    const int t0 = c * CHUNK;
    const int tid  = threadIdx.x;
    const int lane = tid & 63;
    const int w    = tid >> 6;          // wave 0..3
    const int lm   = lane & 15;
    const int lg   = lane >> 4;

    // ---- stage U chunk (f32 -> bf16) into Ul[t][u] ----
    {
        const int t = tid >> 2, q = (tid & 3) * 16;
        const float* up = U + ((size_t)(t0 + t) * NBATCH + b) * NUV + q;
        const float4 f0 = *(const float4*)(up + 0);
        const float4 f1 = *(const float4*)(up + 4);
        const float4 f2 = *(const float4*)(up + 8);
        const float4 f3 = *(const float4*)(up + 12);
        short8v s0, s1;
        s0[0]=(short)f2bf(f0.x); s0[1]=(short)f2bf(f0.y);
        s0[2]=(short)f2bf(f0.z); s0[3]=(short)f2bf(f0.w);
        s0[4]=(short)f2bf(f1.x); s0[5]=(short)f2bf(f1.y);
        s0[6]=(short)f2bf(f1.z); s0[7]=(short)f2bf(f1.w);
        s1[0]=(short)f2bf(f2.x); s1[1]=(short)f2bf(f2.y);
        s1[2]=(short)f2bf(f2.z); s1[3]=(short)f2bf(f2.w);
        s1[4]=(short)f2bf(f3.x); s1[5]=(short)f2bf(f3.y);
        s1[6]=(short)f2bf(f3.z); s1[7]=(short)f2bf(f3.w);
        *(short8v*)&Ul[t*UP + q]     = s0;
        *(short8v*)&Ul[t*UP + q + 8] = s1;
    }
    __syncthreads();

    // ---- GEMM1: wave w owns h'-tiles [w*8, w*8+8), all 4 t-tiles ----
    {
        bf16x8 ufrag[4][2];
        #pragma unroll
        for (int nt = 0; nt < 4; ++nt)
            #pragma unroll
            for (int ks = 0; ks < 2; ++ks)
                ufrag[nt][ks] = *(const bf16x8*)&Ul[(nt*16 + lm)*UP + lg*8 + ks*32];

        #pragma unroll
        for (int i = 0; i < 8; ++i) {
            const int mt = w*8 + i;
            const int hp = mt*16 + lm;                    // A-row h'
            const int ho = (hp >> 1) + ((hp & 1) << 8);   // orig h
            bf16x8 a[2];
            #pragma unroll
            for (int ks = 0; ks < 2; ++ks) {
                const float* bp = B + ho*NUV + lg*8 + ks*32;
                const float4 g0 = *(const float4*)(bp);
                const float4 g1 = *(const float4*)(bp + 4);
                bf16x8 t8;
                t8[0]=(short)f2bf(g0.x); t8[1]=(short)f2bf(g0.y);
                t8[2]=(short)f2bf(g0.z); t8[3]=(short)f2bf(g0.w);
                t8[4]=(short)f2bf(g1.x); t8[5]=(short)f2bf(g1.y);
                t8[6]=(short)f2bf(g1.z); t8[7]=(short)f2bf(g1.w);
                a[ks] = t8;
            }
            #pragma unroll
            for (int nt = 0; nt < 4; ++nt) {
                f32x4 acc = {0.f, 0.f, 0.f, 0.f};
                acc = __builtin_amdgcn_mfma_f32_16x16x32_bf16(a[0], ufrag[nt][0], acc, 0, 0, 0);
                acc = __builtin_amdgcn_mfma_f32_16x16x32_bf16(a[1], ufrag[nt][1], acc, 0, 0, 0);
                const int t  = nt*16 + lm;
                const int hb = mt*16 + lg*4;
                uint2 pk;
                pk.x = f2bf(acc[0]) | (f2bf(acc[1]) << 16);
                pk.y = f2bf(acc[2]) | (f2bf(acc[3]) << 16);
                *(uint2*)&Xl[t*XP + hb] = pk;
            }
        }
    }
    __syncthreads();

    // ---- scan: thread p owns complex pair (h'=2p, 2p+1) ----
    {
        const int p = tid;
        const float Lr = lr[p], Li = li[p];
        float x1, x2;
        if (FINAL) {
            const float* cp = carr + ((size_t)c*NBATCH + b)*NHID + 2*p;
            x1 = cp[0]; x2 = cp[1];
        } else { x1 = 0.f; x2 = 0.f; }
        #pragma unroll 8
        for (int t = 0; t < CHUNK; ++t) {
            const uint d = *(const uint*)&Xl[t*XP + 2*p];
            const float n1 = fmaf(Lr, x1, fmaf(-Li, x2, bf2f_lo(d)));
            const float n2 = fmaf(Li, x1, fmaf( Lr, x2, bf2f_hi(d)));
            x1 = n1; x2 = n2;
            if (FINAL) {
                const uint pk = f2bf(x1) | (f2bf(x2) << 16);
                *(uint*)&Xl[t*XP + 2*p] = pk;
            }
        }
        if (!FINAL) {
            float2* cp = (float2*)(carr + ((size_t)c*NBATCH + b)*NHID + 2*p);
            *cp = make_float2(x1, x2);
        }
    }

    if constexpr (FINAL) {
        __syncthreads();
        // ---- GEMM2: wave w owns y-tile w; 4 t-tiles; K = 512 ----
        const int y = w*16 + lm;
        const float bias = bx2y[y];
        f32x4 acc2[4];
        #pragma unroll
        for (int mt = 0; mt < 4; ++mt) acc2[mt] = (f32x4){bias, bias, bias, bias};

        #pragma unroll
        for (int ks = 0; ks < 16; ++ks) {
            const int p0 = lg*4 + ks*16;
            const float4 wr = *(const float4*)(W + (size_t)y*NHID + p0);
            const float4 wi = *(const float4*)(W + (size_t)y*NHID + NH2 + p0);
            bf16x8 bf;
            bf[0]=(short)f2bf(wr.x); bf[1]=(short)f2bf(wi.x);
            bf[2]=(short)f2bf(wr.y); bf[3]=(short)f2bf(wi.y);
            bf[4]=(short)f2bf(wr.z); bf[5]=(short)f2bf(wi.z);
            bf[6]=(short)f2bf(wr.w); bf[7]=(short)f2bf(wi.w);
            const int kb = lg*8 + ks*32;
            #pragma unroll
            for (int mt = 0; mt < 4; ++mt) {
                const bf16x8 xa = *(const bf16x8*)&Xl[(mt*16 + lm)*XP + kb];
                acc2[mt] = __builtin_amdgcn_mfma_f32_16x16x32_bf16(xa, bf, acc2[mt], 0, 0, 0);
            }
        }
        #pragma unroll
        for (int mt = 0; mt < 4; ++mt) {
            #pragma unroll
            for (int r = 0; r < 4; ++r) {
                const int t = mt*16 + lg*4 + r;
                Y[((size_t)(t0 + t)*NBATCH + b)*NYV + y] = acc2[mt][r];
            }
        }
    }
}

// ---------------------------------------------------------------------------
// Carry propagation (R6 structure; only change: le = fixed-order sum of the
// NSPLIT contiguous partials). carr is now write-only here (entry states).
// ---------------------------------------------------------------------------
__global__ __launch_bounds__(256) void k_carry_prop(
    const float* __restrict__ y0, const float* __restrict__ Wy2x,
    const float* __restrict__ by2x,
    const float* __restrict__ lr, const float* __restrict__ li,
    float* __restrict__ carr, const float* __restrict__ cPart)
{
    const int b = blockIdx.x;
    const int p = threadIdx.x;            // 0..255

    float x1 = by2x[p], x2 = by2x[p + NH2];
    #pragma unroll 8
    for (int yv = 0; yv < NYV; ++yv) {
        const float y0v = y0[b * NYV + yv];
        x1 = fmaf(y0v, Wy2x[p * NYV + yv], x1);
        x2 = fmaf(y0v, Wy2x[(p + NH2) * NYV + yv], x2);
    }

    // Lambda^64 by 6 squarings
    float cr = lr[p], ci = li[p];
    #pragma unroll
    for (int k = 0; k < 6; ++k) {
        const float nr = cr*cr - ci*ci;
        const float ni = 2.f*cr*ci;
        cr = nr; ci = ni;
    }

    for (int c = 0; c < NCHUNK; ++c) {
        const size_t off = ((size_t)c*NBATCH + b)*NHID + 2*p;
        float le1 = 0.f, le2 = 0.f;
        #pragma unroll
        for (int q = 0; q < NSPLIT; ++q) {
            const float2 v = *(const float2*)(cPart + (size_t)q*CPSZ + off);
            le1 += v.x; le2 += v.y;
        }
        carr[off]     = x1;
        carr[off + 1] = x2;
        const float n1 = cr*x1 - ci*x2 + le1;
        const float n2 = ci*x1 + cr*x2 + le2;
        x1 = n1; x2 = n2;
    }
}

extern "C" void kernel_launch(void* const* d_in, const int* in_sizes, int n_in,
                              void* d_out, int out_size, void* d_ws, size_t ws_size,
                              hipStream_t stream) {
    const float* y0   = (const float*)d_in[0];
    const float* U    = (const float*)d_in[1];
    const float* lr   = (const float*)d_in[2];
    const float* li   = (const float*)d_in[3];
    const float* B    = (const float*)d_in[4];
    const float* Wy2x = (const float*)d_in[5];
    const float* by2x = (const float*)d_in[6];
    const float* Wx2y = (const float*)d_in[7];
    const float* bx2y = (const float*)d_in[8];
    float* Y    = (float*)d_out;
    char* ws = (char*)d_ws;
    float* carr  = (float*)(ws);                    // 2 MB
    short* Bmod  = (short*)(ws + (2u<<20));         // 4 MB
    float* cPart = (float*)(ws + (6u<<20));         // 8 x 2 MB = 16 MB
    short* Ubf   = (short*)(ws + (22u<<20));        // 8 MB

    k_cvtU<<<2048, 256, 0, stream>>>(U, Ubf);
    k_bmod<<<dim3(NH2), 64, 0, stream>>>(B, lr, li, Bmod);
    k_bgemm_v4<<<dim3(NCHUNK, 8, NSPLIT), 256, 0, stream>>>(Ubf, Bmod, cPart);
    k_carry_prop<<<NBATCH, 256, 0, stream>>>(y0, Wy2x, by2x, lr, li, carr, cPart);
    k_scan<true><<<dim3(NBATCH, NCHUNK), 256, 0, stream>>>(U, B, lr, li, Wx2y, bx2y, carr, Y);
}

// Round 9
// 102.836 us; speedup vs baseline: 3.2409x; 1.0060x over previous
//
#include <hip/hip_runtime.h>
#include <hip/hip_bf16.h>
#include <cstddef>
#include <cstdint>

#define NYV 64
#define NUV 64
#define NHID 512
#define NH2 256
#define NBATCH 64
#define CHUNK 64            // known-good geometry. CHUNK=32 is poisoned (R3/R4).
#define NCHUNK 16
#define XP 520              // Xl row pitch (bf16 units) -> 1040 B, breaks pow2 stride
#define UP 72               // Ul row pitch (bf16 units) -> 144 B
#define BMK 4096            // Bmod K = CHUNK*NUV
#define NSPLIT 8            // K-split depth for bgemm
#define CPSZ (NCHUNK*NBATCH*NHID)   // floats per partial buffer (524288 = 2 MB)

typedef __attribute__((ext_vector_type(8))) short bf16x8;
typedef __attribute__((ext_vector_type(4))) float f32x4;
typedef __attribute__((ext_vector_type(8))) short short8v;

__device__ __forceinline__ uint f2bf(float f) {
    union { __hip_bfloat16 h; ushort s; } u;
    u.h = __float2bfloat16(f);
    return (uint)u.s;
}
__device__ __forceinline__ float bf2f_lo(uint d) {
    union { uint u; float f; } v; v.u = d << 16; return v.f;
}
__device__ __forceinline__ float bf2f_hi(uint d) {
    union { uint u; float f; } v; v.u = d & 0xffff0000u; return v.f;
}

// h-permutation: h' = 2p (real of pair p) / 2p+1 (imag of pair p)
// orig(h') = (h'>>1) + (h'&1)*256

// ---------------------------------------------------------------------------
// k_cvtU (R6-proven, verbatim): U (f32) -> Ubf (bf16), same [t][b][u] layout.
// ---------------------------------------------------------------------------
__global__ __launch_bounds__(256) void k_cvtU(
    const float* __restrict__ U, short* __restrict__ Ubf)
{
    const size_t g = ((size_t)blockIdx.x * 256 + threadIdx.x) * 8;
    const float4 f0 = *(const float4*)(U + g);
    const float4 f1 = *(const float4*)(U + g + 4);
    short8v s;
    s[0]=(short)f2bf(f0.x); s[1]=(short)f2bf(f0.y);
    s[2]=(short)f2bf(f0.z); s[3]=(short)f2bf(f0.w);
    s[4]=(short)f2bf(f1.x); s[5]=(short)f2bf(f1.y);
    s[6]=(short)f2bf(f1.z); s[7]=(short)f2bf(f1.w);
    *(short8v*)(Ubf + g) = s;
}

// ---------------------------------------------------------------------------
// k_bmod (R5-proven, verbatim): Bmod[2p][j*64+u]   = cr_j*B[p][u] - ci_j*B[p+256][u]
//                               Bmod[2p+1][j*64+u] = ci_j*B[p][u] + cr_j*B[p+256][u]
// with (cr_j, ci_j) = lambda_p^(63-j). grid=256 (p), block=64 (j).
// ---------------------------------------------------------------------------
__global__ __launch_bounds__(64) void k_bmod(
    const float* __restrict__ B, const float* __restrict__ lr,
    const float* __restrict__ li, short* __restrict__ Bmod)
{
    const int p = blockIdx.x;      // 0..255
    const int j = threadIdx.x;     // 0..63
    __shared__ float Bl[2][NUV];
    Bl[0][j] = B[p * NUV + j];
    Bl[1][j] = B[(p + NH2) * NUV + j];
    __syncthreads();

    const float Lr = lr[p], Li = li[p];
    float cr = 1.f, ci = 0.f;
    const int m = (CHUNK - 1) - j;
    for (int i = 0; i < m; ++i) {
        const float nr = cr * Lr - ci * Li;
        const float ni = cr * Li + ci * Lr;
        cr = nr; ci = ni;
    }

    short* r0 = Bmod + (size_t)(2 * p)     * BMK + j * NUV;
    short* r1 = Bmod + (size_t)(2 * p + 1) * BMK + j * NUV;
    #pragma unroll
    for (int u0 = 0; u0 < NUV; u0 += 8) {
        short8v s0, s1;
        #pragma unroll
        for (int k = 0; k < 8; ++k) {
            const float b1 = Bl[0][u0 + k], b2 = Bl[1][u0 + k];
            s0[k] = (short)f2bf(cr * b1 - ci * b2);
            s1[k] = (short)f2bf(ci * b1 + cr * b2);
        }
        *(short8v*)(r0 + u0) = s0;
        *(short8v*)(r1 + u0) = s1;
    }
}

// ---------------------------------------------------------------------------
// k_bgemm_v5: same math/mappings as the R8-proven v4 (per-accumulator FP
// order identical: jj ascending, a0 then a1). Two perf-only changes:
//  (1) depth-2 software pipeline: jj+1 fragments prefetched into the other
//      register slot while jj's MFMAs issue (full unroll -> static indices).
//  (2) XCD swizzle: 1D grid, kq = id&7 so the 8 same-(c,kq) mb-blocks land
//      on one XCD (round-robin) -> per-XCD working set ~576 KB, L2-resident.
// ---------------------------------------------------------------------------
__global__ __launch_bounds__(256) void k_bgemm_v5(
    const short* __restrict__ Ubf, const short* __restrict__ Bmod,
    float* __restrict__ cPart)
{
    const int id  = blockIdx.x;          // 0..1023
    const int kq  = id & 7;              // XCD-co-located
    const int mb  = (id >> 3) & 7;
    const int c   = id >> 6;             // 0..15
    const int tid  = threadIdx.x;
    const int lane = tid & 63;
    const int w    = tid >> 6;           // 0..3
    const int lm   = lane & 15;
    const int lg   = lane >> 4;
    const int t0   = c * CHUNK;

    f32x4 acc[4];
    #pragma unroll
    for (int nt = 0; nt < 4; ++nt) acc[nt] = (f32x4){0.f, 0.f, 0.f, 0.f};

    const int rowA = mb * 64 + w * 16 + lm;
    const short* arow  = Bmod + (size_t)rowA * BMK + (size_t)(kq * 8) * NUV + lg * 8;
    const short* ubase = Ubf + (size_t)(t0 + kq * 8) * (NBATCH * NUV) + lg * 8;

    bf16x8 A0[2], A1[2], U0[2][4], U1[2][4];

    // prologue: jj = 0 into slot 0
    {
        A0[0] = *(const bf16x8*)(arow);
        A1[0] = *(const bf16x8*)(arow + 32);
        #pragma unroll
        for (int nt = 0; nt < 4; ++nt) {
            const short* ur = ubase + (nt * 16 + lm) * NUV;
            U0[0][nt] = *(const bf16x8*)(ur);
            U1[0][nt] = *(const bf16x8*)(ur + 32);
        }
    }

    #pragma unroll
    for (int jj = 0; jj < 8; ++jj) {
        const int cur = jj & 1, nxt = cur ^ 1;
        if (jj < 7) {
            const int jn = jj + 1;
            const short* ar = arow + (size_t)jn * NUV;
            A0[nxt] = *(const bf16x8*)(ar);
            A1[nxt] = *(const bf16x8*)(ar + 32);
            const short* ub = ubase + (size_t)jn * (NBATCH * NUV);
            #pragma unroll
            for (int nt = 0; nt < 4; ++nt) {
                const short* ur = ub + (nt * 16 + lm) * NUV;
                U0[nxt][nt] = *(const bf16x8*)(ur);
                U1[nxt][nt] = *(const bf16x8*)(ur + 32);
            }
        }
        #pragma unroll
        for (int nt = 0; nt < 4; ++nt) {
            acc[nt] = __builtin_amdgcn_mfma_f32_16x16x32_bf16(A0[cur], U0[cur][nt], acc[nt], 0, 0, 0);
            acc[nt] = __builtin_amdgcn_mfma_f32_16x16x32_bf16(A1[cur], U1[cur][nt], acc[nt], 0, 0, 0);
        }
    }

    float* dst = cPart + (size_t)kq * CPSZ;
    const int hb = mb * 64 + w * 16 + lg * 4;
    #pragma unroll
    for (int nt = 0; nt < 4; ++nt) {
        const int b = nt * 16 + lm;
        float4 v;
        v.x = acc[nt][0]; v.y = acc[nt][1];
        v.z = acc[nt][2]; v.w = acc[nt][3];
        *(float4*)&dst[((size_t)c * NBATCH + b) * NHID + hb] = v;
    }
}

// ---------------------------------------------------------------------------
// Pass 3 (R2/R5/R6/R8-proven, VERBATIM): GEMM1 -> scan (seeded) -> GEMM2 -> Y.
// ---------------------------------------------------------------------------
template<bool FINAL>
__global__ __launch_bounds__(256) void k_scan(
    const float* __restrict__ U, const float* __restrict__ B,
    const float* __restrict__ lr, const float* __restrict__ li,
    const float* __restrict__ W, const float* __restrict__ bx2y,
    float* __restrict__ carr, float* __restrict__ Y)
{
    __shared__ short Xl[CHUNK * XP];   // 66,560 B
    __shared__ short Ul[CHUNK * UP];   //  9,216 B

    const int b  = blockIdx.x;
    const int c  = blockIdx.y;
    const int t0 = c * CHUNK;
    const int tid  = threadIdx.x;
    const int lane = tid & 63;
    const int w    = tid >> 6;          // wave 0..3
    const int lm   = lane & 15;
    const int lg   = lane >> 4;

    // ---- stage U chunk (f32 -> bf16) into Ul[t][u] ----
    {
        const int t = tid >> 2, q = (tid & 3) * 16;
        const float* up = U + ((size_t)(t0 + t) * NBATCH + b) * NUV + q;
        const float4 f0 = *(const float4*)(up + 0);
        const float4 f1 = *(const float4*)(up + 4);
        const float4 f2 = *(const float4*)(up + 8);
        const float4 f3 = *(const float4*)(up + 12);
        short8v s0, s1;
        s0[0]=(short)f2bf(f0.x); s0[1]=(short)f2bf(f0.y);
        s0[2]=(short)f2bf(f0.z); s0[3]=(short)f2bf(f0.w);
        s0[4]=(short)f2bf(f1.x); s0[5]=(short)f2bf(f1.y);
        s0[6]=(short)f2bf(f1.z); s0[7]=(short)f2bf(f1.w);
        s1[0]=(short)f2bf(f2.x); s1[1]=(short)f2bf(f2.y);
        s1[2]=(short)f2bf(f2.z); s1[3]=(short)f2bf(f2.w);
        s1[4]=(short)f2bf(f3.x); s1[5]=(short)f2bf(f3.y);
        s1[6]=(short)f2bf(f3.z); s1[7]=(short)f2bf(f3.w);
        *(short8v*)&Ul[t*UP + q]     = s0;
        *(short8v*)&Ul[t*UP + q + 8] = s1;
    }
    __syncthreads();

    // ---- GEMM1: wave w owns h'-tiles [w*8, w*8+8), all 4 t-tiles ----
    {
        bf16x8 ufrag[4][2];
        #pragma unroll
        for (int nt = 0; nt < 4; ++nt)
            #pragma unroll
            for (int ks = 0; ks < 2; ++ks)
                ufrag[nt][ks] = *(const bf16x8*)&Ul[(nt*16 + lm)*UP + lg*8 + ks*32];

        #pragma unroll
        for (int i = 0; i < 8; ++i) {
            const int mt = w*8 + i;
            const int hp = mt*16 + lm;                    // A-row h'
            const int ho = (hp >> 1) + ((hp & 1) << 8);   // orig h
            bf16x8 a[2];
            #pragma unroll
            for (int ks = 0; ks < 2; ++ks) {
                const float* bp = B + ho*NUV + lg*8 + ks*32;
                const float4 g0 = *(const float4*)(bp);
                const float4 g1 = *(const float4*)(bp + 4);
                bf16x8 t8;
                t8[0]=(short)f2bf(g0.x); t8[1]=(short)f2bf(g0.y);
                t8[2]=(short)f2bf(g0.z); t8[3]=(short)f2bf(g0.w);
                t8[4]=(short)f2bf(g1.x); t8[5]=(short)f2bf(g1.y);
                t8[6]=(short)f2bf(g1.z); t8[7]=(short)f2bf(g1.w);
                a[ks] = t8;
            }
            #pragma unroll
            for (int nt = 0; nt < 4; ++nt) {
                f32x4 acc = {0.f, 0.f, 0.f, 0.f};
                acc = __builtin_amdgcn_mfma_f32_16x16x32_bf16(a[0], ufrag[nt][0], acc, 0, 0, 0);
                acc = __builtin_amdgcn_mfma_f32_16x16x32_bf16(a[1], ufrag[nt][1], acc, 0, 0, 0);
                const int t  = nt*16 + lm;
                const int hb = mt*16 + lg*4;
                uint2 pk;
                pk.x = f2bf(acc[0]) | (f2bf(acc[1]) << 16);
                pk.y = f2bf(acc[2]) | (f2bf(acc[3]) << 16);
                *(uint2*)&Xl[t*XP + hb] = pk;
            }
        }
    }
    __syncthreads();

    // ---- scan: thread p owns complex pair (h'=2p, 2p+1) ----
    {
        const int p = tid;
        const float Lr = lr[p], Li = li[p];
        float x1, x2;
        if (FINAL) {
            const float* cp = carr + ((size_t)c*NBATCH + b)*NHID + 2*p;
            x1 = cp[0]; x2 = cp[1];
        } else { x1 = 0.f; x2 = 0.f; }
        #pragma unroll 8
        for (int t = 0; t < CHUNK; ++t) {
            const uint d = *(const uint*)&Xl[t*XP + 2*p];
            const float n1 = fmaf(Lr, x1, fmaf(-Li, x2, bf2f_lo(d)));
            const float n2 = fmaf(Li, x1, fmaf( Lr, x2, bf2f_hi(d)));
            x1 = n1; x2 = n2;
            if (FINAL) {
                const uint pk = f2bf(x1) | (f2bf(x2) << 16);
                *(uint*)&Xl[t*XP + 2*p] = pk;
            }
        }
        if (!FINAL) {
            float2* cp = (float2*)(carr + ((size_t)c*NBATCH + b)*NHID + 2*p);
            *cp = make_float2(x1, x2);
        }
    }

    if constexpr (FINAL) {
        __syncthreads();
        // ---- GEMM2: wave w owns y-tile w; 4 t-tiles; K = 512 ----
        const int y = w*16 + lm;
        const float bias = bx2y[y];
        f32x4 acc2[4];
        #pragma unroll
        for (int mt = 0; mt < 4; ++mt) acc2[mt] = (f32x4){bias, bias, bias, bias};

        #pragma unroll
        for (int ks = 0; ks < 16; ++ks) {
            const int p0 = lg*4 + ks*16;
            const float4 wr = *(const float4*)(W + (size_t)y*NHID + p0);
            const float4 wi = *(const float4*)(W + (size_t)y*NHID + NH2 + p0);
            bf16x8 bf;
            bf[0]=(short)f2bf(wr.x); bf[1]=(short)f2bf(wi.x);
            bf[2]=(short)f2bf(wr.y); bf[3]=(short)f2bf(wi.y);
            bf[4]=(short)f2bf(wr.z); bf[5]=(short)f2bf(wi.z);
            bf[6]=(short)f2bf(wr.w); bf[7]=(short)f2bf(wi.w);
            const int kb = lg*8 + ks*32;
            #pragma unroll
            for (int mt = 0; mt < 4; ++mt) {
                const bf16x8 xa = *(const bf16x8*)&Xl[(mt*16 + lm)*XP + kb];
                acc2[mt] = __builtin_amdgcn_mfma_f32_16x16x32_bf16(xa, bf, acc2[mt], 0, 0, 0);
            }
        }
        #pragma unroll
        for (int mt = 0; mt < 4; ++mt) {
            #pragma unroll
            for (int r = 0; r < 4; ++r) {
                const int t = mt*16 + lg*4 + r;
                Y[((size_t)(t0 + t)*NBATCH + b)*NYV + y] = acc2[mt][r];
            }
        }
    }
}

// ---------------------------------------------------------------------------
// Carry propagation (R8 VERBATIM): le = fixed-order sum of the NSPLIT
// contiguous partials; serial chain over 16 chunks; carr written in place.
// ---------------------------------------------------------------------------
__global__ __launch_bounds__(256) void k_carry_prop(
    const float* __restrict__ y0, const float* __restrict__ Wy2x,
    const float* __restrict__ by2x,
    const float* __restrict__ lr, const float* __restrict__ li,
    float* __restrict__ carr, const float* __restrict__ cPart)
{
    const int b = blockIdx.x;
    const int p = threadIdx.x;            // 0..255

    float x1 = by2x[p], x2 = by2x[p + NH2];
    #pragma unroll 8
    for (int yv = 0; yv < NYV; ++yv) {
        const float y0v = y0[b * NYV + yv];
        x1 = fmaf(y0v, Wy2x[p * NYV + yv], x1);
        x2 = fmaf(y0v, Wy2x[(p + NH2) * NYV + yv], x2);
    }

    // Lambda^64 by 6 squarings
    float cr = lr[p], ci = li[p];
    #pragma unroll
    for (int k = 0; k < 6; ++k) {
        const float nr = cr*cr - ci*ci;
        const float ni = 2.f*cr*ci;
        cr = nr; ci = ni;
    }

    for (int c = 0; c < NCHUNK; ++c) {
        const size_t off = ((size_t)c*NBATCH + b)*NHID + 2*p;
        float le1 = 0.f, le2 = 0.f;
        #pragma unroll
        for (int q = 0; q < NSPLIT; ++q) {
            const float2 v = *(const float2*)(cPart + (size_t)q*CPSZ + off);
            le1 += v.x; le2 += v.y;
        }
        carr[off]     = x1;
        carr[off + 1] = x2;
        const float n1 = cr*x1 - ci*x2 + le1;
        const float n2 = ci*x1 + cr*x2 + le2;
        x1 = n1; x2 = n2;
    }
}

extern "C" void kernel_launch(void* const* d_in, const int* in_sizes, int n_in,
                              void* d_out, int out_size, void* d_ws, size_t ws_size,
                              hipStream_t stream) {
    const float* y0   = (const float*)d_in[0];
    const float* U    = (const float*)d_in[1];
    const float* lr   = (const float*)d_in[2];
    const float* li   = (const float*)d_in[3];
    const float* B    = (const float*)d_in[4];
    const float* Wy2x = (const float*)d_in[5];
    const float* by2x = (const float*)d_in[6];
    const float* Wx2y = (const float*)d_in[7];
    const float* bx2y = (const float*)d_in[8];
    float* Y    = (float*)d_out;
    char* ws = (char*)d_ws;
    float* carr  = (float*)(ws);                    // 2 MB
    short* Bmod  = (short*)(ws + (2u<<20));         // 4 MB
    float* cPart = (float*)(ws + (6u<<20));         // 8 x 2 MB = 16 MB
    short* Ubf   = (short*)(ws + (22u<<20));        // 8 MB

    k_cvtU<<<2048, 256, 0, stream>>>(U, Ubf);
    k_bmod<<<dim3(NH2), 64, 0, stream>>>(B, lr, li, Bmod);
    k_bgemm_v5<<<NCHUNK * 8 * NSPLIT, 256, 0, stream>>>(Ubf, Bmod, cPart);
    k_carry_prop<<<NBATCH, 256, 0, stream>>>(y0, Wy2x, by2x, lr, li, carr, cPart);
    k_scan<true><<<dim3(NBATCH, NCHUNK), 256, 0, stream>>>(U, B, lr, li, Wx2y, bx2y, carr, Y);
}

// Round 10
// 65.617 us; speedup vs baseline: 5.0791x; 1.5672x over previous
//
#include <hip/hip_runtime.h>
#include <hip/hip_bf16.h>
#include <cstddef>
#include <cstdint>

#define NYV 64
#define NUV 64
#define NHID 512
#define NH2 256
#define NBATCH 64
#define CHUNK 64            // known-good geometry. CHUNK=32 is poisoned (R3/R4).
#define NCHUNK 16
#define XP 520              // Xl row pitch (bf16 units) -> 1040 B, breaks pow2 stride
#define UP 72               // Ul row pitch (bf16 units) -> 144 B

typedef __attribute__((ext_vector_type(8))) short bf16x8;
typedef __attribute__((ext_vector_type(4))) float f32x4;
typedef __attribute__((ext_vector_type(8))) short short8v;

__device__ __forceinline__ uint f2bf(float f) {
    union { __hip_bfloat16 h; ushort s; } u;
    u.h = __float2bfloat16(f);
    return (uint)u.s;
}
__device__ __forceinline__ float bf2f_lo(uint d) {
    union { uint u; float f; } v; v.u = d << 16; return v.f;
}
__device__ __forceinline__ float bf2f_hi(uint d) {
    union { uint u; float f; } v; v.u = d & 0xffff0000u; return v.f;
}

// h-permutation: h' = 2p (real of pair p) / 2p+1 (imag of pair p)
// orig(h') = (h'>>1) + (h'&1)*256

// ---------------------------------------------------------------------------
// R2 structure, 2 dispatches (carry_prop folded in):
//  k_scan<false>: stage U -> GEMM1 -> scan from 0 -> write chunk-local end
//                 states to carr. Blocks with c==0 also compute
//                 x0 = y0@Wy2x^T + by2x -> x0buf  (R2 carry_prop's exact code).
//  k_scan<true> : stage U -> GEMM1 -> seed = per-thread carry chain
//                 (x0buf + Lambda^64-weighted sum of carr[cc<c], identical
//                 op order to R2 carry_prop -> bit-identical seeds)
//                 -> scan -> GEMM2 -> Y.
// Interior of both kernels is R2 VERBATIM (R3/R7 lesson: no load hoisting).
// ---------------------------------------------------------------------------
template<bool FINAL>
__global__ __launch_bounds__(256) void k_scan(
    const float* __restrict__ U, const float* __restrict__ B,
    const float* __restrict__ lr, const float* __restrict__ li,
    const float* __restrict__ W, const float* __restrict__ bx2y,
    const float* __restrict__ y0, const float* __restrict__ Wy2x,
    const float* __restrict__ by2x,
    float* __restrict__ carr, float* __restrict__ x0buf,
    float* __restrict__ Y)
{
    __shared__ short Xl[CHUNK * XP];   // 66,560 B
    __shared__ short Ul[CHUNK * UP];   //  9,216 B

    const int b  = blockIdx.x;
    const int c  = blockIdx.y;
    const int t0 = c * CHUNK;
    const int tid  = threadIdx.x;
    const int lane = tid & 63;
    const int w    = tid >> 6;          // wave 0..3
    const int lm   = lane & 15;
    const int lg   = lane >> 4;

    // ---- stage U chunk (f32 -> bf16) into Ul[t][u] (R2 verbatim) ----
    {
        const int t = tid >> 2, q = (tid & 3) * 16;
        const float* up = U + ((size_t)(t0 + t) * NBATCH + b) * NUV + q;
        const float4 f0 = *(const float4*)(up + 0);
        const float4 f1 = *(const float4*)(up + 4);
        const float4 f2 = *(const float4*)(up + 8);
        const float4 f3 = *(const float4*)(up + 12);
        short8v s0, s1;
        s0[0]=(short)f2bf(f0.x); s0[1]=(short)f2bf(f0.y);
        s0[2]=(short)f2bf(f0.z); s0[3]=(short)f2bf(f0.w);
        s0[4]=(short)f2bf(f1.x); s0[5]=(short)f2bf(f1.y);
        s0[6]=(short)f2bf(f1.z); s0[7]=(short)f2bf(f1.w);
        s1[0]=(short)f2bf(f2.x); s1[1]=(short)f2bf(f2.y);
        s1[2]=(short)f2bf(f2.z); s1[3]=(short)f2bf(f2.w);
        s1[4]=(short)f2bf(f3.x); s1[5]=(short)f2bf(f3.y);
        s1[6]=(short)f2bf(f3.z); s1[7]=(short)f2bf(f3.w);
        *(short8v*)&Ul[t*UP + q]     = s0;
        *(short8v*)&Ul[t*UP + q + 8] = s1;
    }
    __syncthreads();

    // ---- GEMM1 (R2 verbatim): wave w owns h'-tiles [w*8, w*8+8), 4 t-tiles ----
    {
        bf16x8 ufrag[4][2];
        #pragma unroll
        for (int nt = 0; nt < 4; ++nt)
            #pragma unroll
            for (int ks = 0; ks < 2; ++ks)
                ufrag[nt][ks] = *(const bf16x8*)&Ul[(nt*16 + lm)*UP + lg*8 + ks*32];

        #pragma unroll
        for (int i = 0; i < 8; ++i) {
            const int mt = w*8 + i;
            const int hp = mt*16 + lm;                    // A-row h'
            const int ho = (hp >> 1) + ((hp & 1) << 8);   // orig h
            bf16x8 a[2];
            #pragma unroll
            for (int ks = 0; ks < 2; ++ks) {
                const float* bp = B + ho*NUV + lg*8 + ks*32;
                const float4 g0 = *(const float4*)(bp);
                const float4 g1 = *(const float4*)(bp + 4);
                bf16x8 t8;
                t8[0]=(short)f2bf(g0.x); t8[1]=(short)f2bf(g0.y);
                t8[2]=(short)f2bf(g0.z); t8[3]=(short)f2bf(g0.w);
                t8[4]=(short)f2bf(g1.x); t8[5]=(short)f2bf(g1.y);
                t8[6]=(short)f2bf(g1.z); t8[7]=(short)f2bf(g1.w);
                a[ks] = t8;
            }
            #pragma unroll
            for (int nt = 0; nt < 4; ++nt) {
                f32x4 acc = {0.f, 0.f, 0.f, 0.f};
                acc = __builtin_amdgcn_mfma_f32_16x16x32_bf16(a[0], ufrag[nt][0], acc, 0, 0, 0);
                acc = __builtin_amdgcn_mfma_f32_16x16x32_bf16(a[1], ufrag[nt][1], acc, 0, 0, 0);
                const int t  = nt*16 + lm;
                const int hb = mt*16 + lg*4;
                uint2 pk;
                pk.x = f2bf(acc[0]) | (f2bf(acc[1]) << 16);
                pk.y = f2bf(acc[2]) | (f2bf(acc[3]) << 16);
                *(uint2*)&Xl[t*XP + hb] = pk;
            }
        }
    }
    __syncthreads();

    // ---- scan: thread p owns complex pair (h'=2p, 2p+1) ----
    {
        const int p = tid;
        const float Lr = lr[p], Li = li[p];
        float x1, x2;
        if (FINAL) {
            // seed = carry chain (replaces R2's carr entry-state read; same
            // position in the kernel). Identical op order to R2 carry_prop:
            // x0, then for cc ascending: x = L64*x + le[cc].
            const float2 x0v = *(const float2*)(x0buf + (size_t)b*NHID + 2*p);
            x1 = x0v.x; x2 = x0v.y;
            float cr = Lr, ci = Li;           // Lambda^64 by 6 squarings
            #pragma unroll
            for (int k = 0; k < 6; ++k) {
                const float nr = cr*cr - ci*ci;
                const float ni = 2.f*cr*ci;
                cr = nr; ci = ni;
            }
            for (int cc = 0; cc < c; ++cc) {
                const float2 le = *(const float2*)(carr + ((size_t)cc*NBATCH + b)*NHID + 2*p);
                const float n1 = cr*x1 - ci*x2 + le.x;
                const float n2 = ci*x1 + cr*x2 + le.y;
                x1 = n1; x2 = n2;
            }
        } else { x1 = 0.f; x2 = 0.f; }
        #pragma unroll 8
        for (int t = 0; t < CHUNK; ++t) {
            const uint d = *(const uint*)&Xl[t*XP + 2*p];
            const float n1 = fmaf(Lr, x1, fmaf(-Li, x2, bf2f_lo(d)));
            const float n2 = fmaf(Li, x1, fmaf( Lr, x2, bf2f_hi(d)));
            x1 = n1; x2 = n2;
            if (FINAL) {
                const uint pk = f2bf(x1) | (f2bf(x2) << 16);
                *(uint*)&Xl[t*XP + 2*p] = pk;
            }
        }
        if (!FINAL) {
            float2* cp = (float2*)(carr + ((size_t)c*NBATCH + b)*NHID + 2*p);
            *cp = make_float2(x1, x2);
        }
    }

    if constexpr (!FINAL) {
        // ---- x0 for batch b (c==0 blocks only): R2 carry_prop's exact code ----
        if (c == 0) {
            const int p = tid;
            float x1 = by2x[p], x2 = by2x[p + NH2];
            #pragma unroll 8
            for (int yv = 0; yv < NYV; ++yv) {
                const float y0v = y0[b * NYV + yv];
                x1 = fmaf(y0v, Wy2x[p * NYV + yv], x1);
                x2 = fmaf(y0v, Wy2x[(p + NH2) * NYV + yv], x2);
            }
            *(float2*)(x0buf + (size_t)b * NHID + 2 * p) = make_float2(x1, x2);
        }
    }

    if constexpr (FINAL) {
        __syncthreads();
        // ---- GEMM2 (R2 verbatim): wave w owns y-tile w; 4 t-tiles; K=512 ----
        const int y = w*16 + lm;
        const float bias = bx2y[y];
        f32x4 acc2[4];
        #pragma unroll
        for (int mt = 0; mt < 4; ++mt) acc2[mt] = (f32x4){bias, bias, bias, bias};

        #pragma unroll
        for (int ks = 0; ks < 16; ++ks) {
            const int p0 = lg*4 + ks*16;
            const float4 wr = *(const float4*)(W + (size_t)y*NHID + p0);
            const float4 wi = *(const float4*)(W + (size_t)y*NHID + NH2 + p0);
            bf16x8 bf;
            bf[0]=(short)f2bf(wr.x); bf[1]=(short)f2bf(wi.x);
            bf[2]=(short)f2bf(wr.y); bf[3]=(short)f2bf(wi.y);
            bf[4]=(short)f2bf(wr.z); bf[5]=(short)f2bf(wi.z);
            bf[6]=(short)f2bf(wr.w); bf[7]=(short)f2bf(wi.w);
            const int kb = lg*8 + ks*32;
            #pragma unroll
            for (int mt = 0; mt < 4; ++mt) {
                const bf16x8 xa = *(const bf16x8*)&Xl[(mt*16 + lm)*XP + kb];
                acc2[mt] = __builtin_amdgcn_mfma_f32_16x16x32_bf16(xa, bf, acc2[mt], 0, 0, 0);
            }
        }
        #pragma unroll
        for (int mt = 0; mt < 4; ++mt) {
            #pragma unroll
            for (int r = 0; r < 4; ++r) {
                const int t = mt*16 + lg*4 + r;
                Y[((size_t)(t0 + t)*NBATCH + b)*NYV + y] = acc2[mt][r];
            }
        }
    }
}

extern "C" void kernel_launch(void* const* d_in, const int* in_sizes, int n_in,
                              void* d_out, int out_size, void* d_ws, size_t ws_size,
                              hipStream_t stream) {
    const float* y0   = (const float*)d_in[0];
    const float* U    = (const float*)d_in[1];
    const float* lr   = (const float*)d_in[2];
    const float* li   = (const float*)d_in[3];
    const float* B    = (const float*)d_in[4];
    const float* Wy2x = (const float*)d_in[5];
    const float* by2x = (const float*)d_in[6];
    const float* Wx2y = (const float*)d_in[7];
    const float* bx2y = (const float*)d_in[8];
    float* Y    = (float*)d_out;
    char* ws = (char*)d_ws;
    float* carr  = (float*)(ws);                    // chunk-local end states, 2 MB
    float* x0buf = (float*)(ws + (2u<<20));         // x0 per batch, 128 KB

    dim3 grid(NBATCH, NCHUNK);
    k_scan<false><<<grid, 256, 0, stream>>>(U, B, lr, li, Wx2y, bx2y,
                                            y0, Wy2x, by2x, carr, x0buf, Y);
    k_scan<true ><<<grid, 256, 0, stream>>>(U, B, lr, li, Wx2y, bx2y,
                                            y0, Wy2x, by2x, carr, x0buf, Y);
}

// Round 13
// 65.505 us; speedup vs baseline: 5.0878x; 1.0017x over previous
//
#include <hip/hip_runtime.h>
#include <hip/hip_bf16.h>
#include <cstddef>
#include <cstdint>

#define NYV 64
#define NUV 64
#define NHID 512
#define NH2 256
#define NBATCH 64
#define CHUNK 64            // known-good geometry. CHUNK=32 poisoned (R3/R4);
                            // ALL interior restructures banned (R3/R4/R7/R11/R12:
                            // 5 failures incl. provably value-identical transforms).
#define NCHUNK 16
#define XP 520              // Xl row pitch (bf16 units) -> 1040 B, breaks pow2 stride
#define UP 72               // Ul row pitch (bf16 units) -> 144 B

typedef __attribute__((ext_vector_type(8))) short bf16x8;
typedef __attribute__((ext_vector_type(4))) float f32x4;
typedef __attribute__((ext_vector_type(8))) short short8v;

__device__ __forceinline__ uint f2bf(float f) {
    union { __hip_bfloat16 h; ushort s; } u;
    u.h = __float2bfloat16(f);
    return (uint)u.s;
}
__device__ __forceinline__ float bf2f_lo(uint d) {
    union { uint u; float f; } v; v.u = d << 16; return v.f;
}
__device__ __forceinline__ float bf2f_hi(uint d) {
    union { uint u; float f; } v; v.u = d & 0xffff0000u; return v.f;
}

// h-permutation: h' = 2p (real of pair p) / 2p+1 (imag of pair p)
// orig(h') = (h'>>1) + (h'&1)*256

// ---------------------------------------------------------------------------
// R10 FINAL (verified best: 65.6 us, absmax 0.0625, deterministic).
// 2 dispatches, carry_prop folded in:
//  k_scan<false>: stage U -> GEMM1 -> scan from 0 -> chunk-local end states
//                 -> carr. c==0 blocks also compute x0 = y0@Wy2x^T + by2x.
//  k_scan<true> : stage U -> GEMM1 -> seed = per-thread carry chain
//                 (x0 + Lambda^64-weighted carr[cc<c], R2-carry_prop op order)
//                 -> scan -> GEMM2 -> Y.
// ---------------------------------------------------------------------------
template<bool FINAL>
__global__ __launch_bounds__(256) void k_scan(
    const float* __restrict__ U, const float* __restrict__ B,
    const float* __restrict__ lr, const float* __restrict__ li,
    const float* __restrict__ W, const float* __restrict__ bx2y,
    const float* __restrict__ y0, const float* __restrict__ Wy2x,
    const float* __restrict__ by2x,
    float* __restrict__ carr, float* __restrict__ x0buf,
    float* __restrict__ Y)
{
    __shared__ short Xl[CHUNK * XP];   // 66,560 B
    __shared__ short Ul[CHUNK * UP];   //  9,216 B

    const int b  = blockIdx.x;
    const int c  = blockIdx.y;
    const int t0 = c * CHUNK;
    const int tid  = threadIdx.x;
    const int lane = tid & 63;
    const int w    = tid >> 6;          // wave 0..3
    const int lm   = lane & 15;
    const int lg   = lane >> 4;

    // ---- stage U chunk (f32 -> bf16) into Ul[t][u] ----
    {
        const int t = tid >> 2, q = (tid & 3) * 16;
        const float* up = U + ((size_t)(t0 + t) * NBATCH + b) * NUV + q;
        const float4 f0 = *(const float4*)(up + 0);
        const float4 f1 = *(const float4*)(up + 4);
        const float4 f2 = *(const float4*)(up + 8);
        const float4 f3 = *(const float4*)(up + 12);
        short8v s0, s1;
        s0[0]=(short)f2bf(f0.x); s0[1]=(short)f2bf(f0.y);
        s0[2]=(short)f2bf(f0.z); s0[3]=(short)f2bf(f0.w);
        s0[4]=(short)f2bf(f1.x); s0[5]=(short)f2bf(f1.y);
        s0[6]=(short)f2bf(f1.z); s0[7]=(short)f2bf(f1.w);
        s1[0]=(short)f2bf(f2.x); s1[1]=(short)f2bf(f2.y);
        s1[2]=(short)f2bf(f2.z); s1[3]=(short)f2bf(f2.w);
        s1[4]=(short)f2bf(f3.x); s1[5]=(short)f2bf(f3.y);
        s1[6]=(short)f2bf(f3.z); s1[7]=(short)f2bf(f3.w);
        *(short8v*)&Ul[t*UP + q]     = s0;
        *(short8v*)&Ul[t*UP + q + 8] = s1;
    }
    __syncthreads();

    // ---- GEMM1: wave w owns h'-tiles [w*8, w*8+8), all 4 t-tiles ----
    {
        bf16x8 ufrag[4][2];
        #pragma unroll
        for (int nt = 0; nt < 4; ++nt)
            #pragma unroll
            for (int ks = 0; ks < 2; ++ks)
                ufrag[nt][ks] = *(const bf16x8*)&Ul[(nt*16 + lm)*UP + lg*8 + ks*32];

        #pragma unroll
        for (int i = 0; i < 8; ++i) {
            const int mt = w*8 + i;
            const int hp = mt*16 + lm;                    // A-row h'
            const int ho = (hp >> 1) + ((hp & 1) << 8);   // orig h
            bf16x8 a[2];
            #pragma unroll
            for (int ks = 0; ks < 2; ++ks) {
                const float* bp = B + ho*NUV + lg*8 + ks*32;
                const float4 g0 = *(const float4*)(bp);
                const float4 g1 = *(const float4*)(bp + 4);
                bf16x8 t8;
                t8[0]=(short)f2bf(g0.x); t8[1]=(short)f2bf(g0.y);
                t8[2]=(short)f2bf(g0.z); t8[3]=(short)f2bf(g0.w);
                t8[4]=(short)f2bf(g1.x); t8[5]=(short)f2bf(g1.y);
                t8[6]=(short)f2bf(g1.z); t8[7]=(short)f2bf(g1.w);
                a[ks] = t8;
            }
            #pragma unroll
            for (int nt = 0; nt < 4; ++nt) {
                f32x4 acc = {0.f, 0.f, 0.f, 0.f};
                acc = __builtin_amdgcn_mfma_f32_16x16x32_bf16(a[0], ufrag[nt][0], acc, 0, 0, 0);
                acc = __builtin_amdgcn_mfma_f32_16x16x32_bf16(a[1], ufrag[nt][1], acc, 0, 0, 0);
                const int t  = nt*16 + lm;
                const int hb = mt*16 + lg*4;
                uint2 pk;
                pk.x = f2bf(acc[0]) | (f2bf(acc[1]) << 16);
                pk.y = f2bf(acc[2]) | (f2bf(acc[3]) << 16);
                *(uint2*)&Xl[t*XP + hb] = pk;
            }
        }
    }
    __syncthreads();

    // ---- scan: thread p owns complex pair (h'=2p, 2p+1) ----
    {
        const int p = tid;
        const float Lr = lr[p], Li = li[p];
        float x1, x2;
        if (FINAL) {
            // seed = carry chain (R2 carry_prop op order -> bit-identical seeds)
            const float2 x0v = *(const float2*)(x0buf + (size_t)b*NHID + 2*p);
            x1 = x0v.x; x2 = x0v.y;
            float cr = Lr, ci = Li;           // Lambda^64 by 6 squarings
            #pragma unroll
            for (int k = 0; k < 6; ++k) {
                const float nr = cr*cr - ci*ci;
                const float ni = 2.f*cr*ci;
                cr = nr; ci = ni;
            }
            for (int cc = 0; cc < c; ++cc) {
                const float2 le = *(const float2*)(carr + ((size_t)cc*NBATCH + b)*NHID + 2*p);
                const float n1 = cr*x1 - ci*x2 + le.x;
                const float n2 = ci*x1 + cr*x2 + le.y;
                x1 = n1; x2 = n2;
            }
        } else { x1 = 0.f; x2 = 0.f; }
        #pragma unroll 8
        for (int t = 0; t < CHUNK; ++t) {
            const uint d = *(const uint*)&Xl[t*XP + 2*p];
            const float n1 = fmaf(Lr, x1, fmaf(-Li, x2, bf2f_lo(d)));
            const float n2 = fmaf(Li, x1, fmaf( Lr, x2, bf2f_hi(d)));
            x1 = n1; x2 = n2;
            if (FINAL) {
                const uint pk = f2bf(x1) | (f2bf(x2) << 16);
                *(uint*)&Xl[t*XP + 2*p] = pk;
            }
        }
        if (!FINAL) {
            float2* cp = (float2*)(carr + ((size_t)c*NBATCH + b)*NHID + 2*p);
            *cp = make_float2(x1, x2);
        }
    }

    if constexpr (!FINAL) {
        // ---- x0 for batch b (c==0 blocks only) ----
        if (c == 0) {
            const int p = tid;
            float x1 = by2x[p], x2 = by2x[p + NH2];
            #pragma unroll 8
            for (int yv = 0; yv < NYV; ++yv) {
                const float y0v = y0[b * NYV + yv];
                x1 = fmaf(y0v, Wy2x[p * NYV + yv], x1);
                x2 = fmaf(y0v, Wy2x[(p + NH2) * NYV + yv], x2);
            }
            *(float2*)(x0buf + (size_t)b * NHID + 2 * p) = make_float2(x1, x2);
        }
    }

    if constexpr (FINAL) {
        __syncthreads();
        // ---- GEMM2: wave w owns y-tile w; 4 t-tiles; K = 512 ----
        const int y = w*16 + lm;
        const float bias = bx2y[y];
        f32x4 acc2[4];
        #pragma unroll
        for (int mt = 0; mt < 4; ++mt) acc2[mt] = (f32x4){bias, bias, bias, bias};

        #pragma unroll
        for (int ks = 0; ks < 16; ++ks) {
            const int p0 = lg*4 + ks*16;
            const float4 wr = *(const float4*)(W + (size_t)y*NHID + p0);
            const float4 wi = *(const float4*)(W + (size_t)y*NHID + NH2 + p0);
            bf16x8 bf;
            bf[0]=(short)f2bf(wr.x); bf[1]=(short)f2bf(wi.x);
            bf[2]=(short)f2bf(wr.y); bf[3]=(short)f2bf(wi.y);
            bf[4]=(short)f2bf(wr.z); bf[5]=(short)f2bf(wi.z);
            bf[6]=(short)f2bf(wr.w); bf[7]=(short)f2bf(wi.w);
            const int kb = lg*8 + ks*32;
            #pragma unroll
            for (int mt = 0; mt < 4; ++mt) {
                const bf16x8 xa = *(const bf16x8*)&Xl[(mt*16 + lm)*XP + kb];
                acc2[mt] = __builtin_amdgcn_mfma_f32_16x16x32_bf16(xa, bf, acc2[mt], 0, 0, 0);
            }
        }
        #pragma unroll
        for (int mt = 0; mt < 4; ++mt) {
            #pragma unroll
            for (int r = 0; r < 4; ++r) {
                const int t = mt*16 + lg*4 + r;
                Y[((size_t)(t0 + t)*NBATCH + b)*NYV + y] = acc2[mt][r];
            }
        }
    }
}

extern "C" void kernel_launch(void* const* d_in, const int* in_sizes, int n_in,
                              void* d_out, int out_size, void* d_ws, size_t ws_size,
                              hipStream_t stream) {
    const float* y0   = (const float*)d_in[0];
    const float* U    = (const float*)d_in[1];
    const float* lr   = (const float*)d_in[2];
    const float* li   = (const float*)d_in[3];
    const float* B    = (const float*)d_in[4];
    const float* Wy2x = (const float*)d_in[5];
    const float* by2x = (const float*)d_in[6];
    const float* Wx2y = (const float*)d_in[7];
    const float* bx2y = (const float*)d_in[8];
    float* Y    = (float*)d_out;
    char* ws = (char*)d_ws;
    float* carr  = (float*)(ws);                    // chunk-local end states, 2 MB
    float* x0buf = (float*)(ws + (2u<<20));         // x0 per batch, 128 KB

    dim3 grid(NBATCH, NCHUNK);
    k_scan<false><<<grid, 256, 0, stream>>>(U, B, lr, li, Wx2y, bx2y,
                                            y0, Wy2x, by2x, carr, x0buf, Y);
    k_scan<true ><<<grid, 256, 0, stream>>>(U, B, lr, li, Wx2y, bx2y,
                                            y0, Wy2x, by2x, carr, x0buf, Y);
}